// Round 19
// baseline (865.274 us; speedup 1.0000x reference)
//
#include <hip/hip_runtime.h>

// GNN_MLP R19: single fused kernel, 977 blocks, software grid barriers.
// __launch_bounds__(256,4) + LDS 19.5KB + grid<=1024 guarantees co-residency
// (4 blocks/CU capacity) -> sense-counter barrier w/ device-scope atomics is
// deadlock-free; no cooperative API (graph-capture safe). Phases = R18's
// proven kernels verbatim: pass1 (LDS-hist sliced scatter), pass2+conv1
// (counting sort + register conv1), conv2+pool (half-tile epilogue), MLP.
// Removes 3 kernel boundaries + 1 memset + kMLP dispatch.
// ninfo packs (a0, a1, indeg<=31 in a1 low-5 mantissa bits) into 8B (4MB).
// Algebra: conv = segsum((h@W+b)[src],dst) = segsum(h[src])@W + indeg*b.

#define TPB 256
#define SBK_BITS 9            // bucket = 512 nodes
#define SBK 512
#define NSBX 1024             // max buckets (N < 524288)
#define CAPX 576              // per (slice,bucket) capacity: mean 320, +14 sigma
#define CAPS 3072             // sorted edges per bucket: mean 2560, +10 sigma
#define PE1 4096              // edges per pass-1 chunk
#define SMEM_BYTES 19456      // union: max(P1 4KB, P2 15.4KB, P3 19.5KB)

typedef unsigned int uint32;

__device__ __forceinline__ float reluf(float v) { return v > 0.f ? v : 0.f; }

__device__ __forceinline__ void gridSync(int* cnt, int* gen, int nb, int round) {
    __syncthreads();
    if (threadIdx.x == 0) {
        __threadfence();
        int v = __hip_atomic_fetch_add(cnt, 1, __ATOMIC_ACQ_REL, __HIP_MEMORY_SCOPE_AGENT);
        if (v == nb - 1) {
            __hip_atomic_store(cnt, 0, __ATOMIC_RELAXED, __HIP_MEMORY_SCOPE_AGENT);
            __hip_atomic_fetch_add(gen, 1, __ATOMIC_RELEASE, __HIP_MEMORY_SCOPE_AGENT);
        } else {
            while (__hip_atomic_load(gen, __ATOMIC_ACQUIRE, __HIP_MEMORY_SCOPE_AGENT) <= round)
                __builtin_amdgcn_s_sleep(16);
        }
    }
    __syncthreads();
}

__device__ __forceinline__ int rowEnd(const int* __restrict__ rowptr,
                                      const int* __restrict__ supEnd, int i, int N) {
    int nxt = i + 1;
    return (nxt >= N || (nxt & (SBK - 1)) == 0) ? supEnd[i >> SBK_BITS] : rowptr[nxt];
}

__device__ __forceinline__ void addMsg(float* a, uint2 q,
                                       const float* __restrict__ W1,
                                       const float* __restrict__ b1) {
    float n0 = __uint_as_float(q.x);
    float ndeg = (float)(q.y & 31u);
    float n1 = __uint_as_float(q.y & ~31u);
#pragma unroll
    for (int j = 0; j < 16; j++)
        a[j] += reluf(fmaf(n0, W1[j], fmaf(n1, W1[16 + j], ndeg * b1[j])));
}

__device__ __forceinline__ int lower_bound(const int* __restrict__ a, int n, int v) {
    int lo = 0, hi = n;
    while (lo < hi) {
        int m = (lo + hi) >> 1;
        if (a[m] < v) lo = m + 1; else hi = m;
    }
    return lo;
}

__global__ void __launch_bounds__(TPB, 4)
kFused(const int* __restrict__ src, const int* __restrict__ dst,
       const float* __restrict__ x, const int* __restrict__ batch,
       const float* __restrict__ W1, const float* __restrict__ b1,
       const float* __restrict__ W2, const float* __restrict__ b2,
       const float* __restrict__ Wf1, const float* __restrict__ bf1,
       const float* __restrict__ Wf2, const float* __restrict__ bf2,
       int* __restrict__ bar, int* __restrict__ curx,
       int* __restrict__ supEnd, int* __restrict__ rowptr,
       uint2* __restrict__ ninfo, float* __restrict__ pooled,
       int* __restrict__ part1x, int* __restrict__ partS,
       float* __restrict__ out, int N, int E, int G, int NSB, int NB1) {
    __shared__ char smem[SMEM_BYTES];
    int bid = blockIdx.x, t = threadIdx.x;
    int nb = gridDim.x;

    // ---- P0: zero pooled (visible to P3 via two barrier crossings) ----
    for (int z = bid * TPB + t; z < 32 * G; z += nb * TPB) pooled[z] = 0.f;

    // ---- P1: pass1 — LDS-hist sliced scatter. word = src<<9 | dst&511 ----
    for (int c = bid; c < NB1; c += nb) {
        int* h = (int*)smem;               // 4 KB
        for (int i = t; i < NSBX; i += TPB) h[i] = 0;
        __syncthreads();
        int base = c * PE1;
        int end = base + PE1 < E ? base + PE1 : E;
        for (int e = base + t; e < end; e += TPB)
            atomicAdd(&h[dst[e] >> SBK_BITS], 1);
        __syncthreads();
        int slice = c & 7;                 // ~XCD under round-robin dispatch
        int* cur = curx + slice * NSBX;
        int rbase = slice * (NSBX * CAPX);
        for (int i = t; i < NSBX; i += TPB) {
            int cc = h[i];
            if (cc) h[i] = i * CAPX + atomicAdd(&cur[i], cc);
        }
        __syncthreads();
        for (int e = base + t; e < end; e += TPB) {
            int d = dst[e];
            int b = d >> SBK_BITS;
            int pos = atomicAdd(&h[b], 1);
            if (pos < (b + 1) * CAPX)      // overflow guard
                part1x[rbase + pos] = (src[e] << SBK_BITS) | (d & (SBK - 1));
        }
        __syncthreads();
    }
    gridSync(bar, bar + 1, nb, 0);

    // ---- P2: pass2 + fused conv1 per bucket ----
    {
        int* hist = (int*)smem;                         // 2 KB
        int* ps   = (int*)(smem + SBK * 4);             // 1 KB
        int* segc = (int*)(smem + SBK * 4 + TPB * 4);   // 32 B
        int* sls  = (int*)(smem + SBK * 4 + TPB * 4 + 64);  // 12 KB
        for (int sb = bid; sb < NSB; sb += nb) {
            int node0 = sb << SBK_BITS;
            int sbase = sb * CAPS;
            for (int i = t; i < SBK; i += TPB) hist[i] = 0;
            if (t < 8) {
                int c = curx[t * NSBX + sb];
                segc[t] = c > CAPX ? CAPX : c;
            }
            __syncthreads();
            for (int seg = 0; seg < 8; seg++) {
                const int* p = part1x + seg * (NSBX * CAPX) + sb * CAPX;
                int c = segc[seg];
                for (int i = t; i < c; i += TPB)
                    atomicAdd(&hist[p[i] & (SBK - 1)], 1);
            }
            __syncthreads();
            int v0 = hist[2 * t], v1 = hist[2 * t + 1];
            int s = v0 + v1;
            ps[t] = s;
            __syncthreads();
            for (int off = 1; off < TPB; off <<= 1) {
                int u = (t >= off) ? ps[t - off] : 0;
                __syncthreads();
                ps[t] += u;
                __syncthreads();
            }
            int start0 = ps[t] - s;
            int start1 = start0 + v0;
            int n0 = node0 + 2 * t, n1 = n0 + 1;
            if (n0 < N) rowptr[n0] = sbase + start0;
            if (n1 < N) rowptr[n1] = sbase + start1;
            hist[2 * t] = start0;          // own slots only -> no race
            hist[2 * t + 1] = start1;
            if (t == TPB - 1) supEnd[sb] = sbase + ps[t];
            __syncthreads();
            for (int seg = 0; seg < 8; seg++) {
                const int* p = part1x + seg * (NSBX * CAPX) + sb * CAPX;
                int c = segc[seg];
                for (int i = t; i < c; i += TPB) {
                    int w = p[i];
                    int slot = atomicAdd(&hist[w & (SBK - 1)], 1);
                    if (slot < CAPS) {
                        int sid = w >> SBK_BITS;
                        partS[sbase + slot] = sid;
                        sls[slot] = sid;
                    }
                }
            }
            __syncthreads();
#pragma unroll
            for (int half = 0; half < 2; half++) {
                int n = half ? n1 : n0;
                if (n >= N) continue;
                int st = half ? start1 : start0;
                int dg = half ? v1 : v0;
                int en = st + dg; if (en > CAPS) en = CAPS;
                float2 sv = ((const float2*)x)[n];
                float a0 = sv.x, a1 = sv.y;
                for (int e = st; e < en; e++) {
                    float2 xv = ((const float2*)x)[sls[e]];
                    a0 += xv.x; a1 += xv.y;
                }
                int indeg = dg + 1;        // + self loop
                if (indeg > 31) indeg = 31;
                ninfo[n] = make_uint2(__float_as_uint(a0),
                                      (__float_as_uint(a1) & ~31u) | (uint32)indeg);
            }
            __syncthreads();
        }
    }
    gridSync(bar, bar + 1, nb, 1);

    // ---- P3: conv2 + fused mean-pool, half-tile epilogue ----
    {
        float* srow = (float*)smem;                       // 17.4 KB
        int* sbat   = (int*)(smem + TPB * 17 * 4);        // 1 KB
        float* spart = (float*)(smem + TPB * 17 * 4 + TPB * 4);  // 1 KB
        int nTiles = (N + TPB - 1) / TPB;
        for (int tile = bid; tile < nTiles; tile += nb) {
            int node0 = tile * TPB;
            int i = node0 + t;
            bool valid = i < N;
            float a[16];
            float sdeg = 0.f;
            if (valid) {
                int rs = rowptr[i];
                int re = rowEnd(rowptr, supEnd, i, N);
                uint2 p = ninfo[i];
                float s0 = __uint_as_float(p.x);
                sdeg = (float)(p.y & 31u);
                float s1 = __uint_as_float(p.y & ~31u);
#pragma unroll
                for (int j = 0; j < 16; j++)
                    a[j] = reluf(fmaf(s0, W1[j], fmaf(s1, W1[16 + j], sdeg * b1[j])));
                int e = rs;
                for (; e + 4 <= re; e += 4) {   // 4 gathers in flight
                    int w0 = partS[e], w1 = partS[e + 1], w2 = partS[e + 2], w3 = partS[e + 3];
                    uint2 q0 = ninfo[w0], q1 = ninfo[w1], q2 = ninfo[w2], q3 = ninfo[w3];
                    addMsg(a, q0, W1, b1);
                    addMsg(a, q1, W1, b1);
                    addMsg(a, q2, W1, b1);
                    addMsg(a, q3, W1, b1);
                }
                for (; e < re; e++)
                    addMsg(a, ninfo[partS[e]], W1, b1);
                sbat[t] = batch[i];
            } else {
#pragma unroll
                for (int j = 0; j < 16; j++) a[j] = 0.f;
                sbat[t] = -1;
            }
            __syncthreads();
            int lastl = N - 1 - node0;
            if (lastl > TPB - 1) lastl = TPB - 1;
            int g0 = sbat[0], g1 = sbat[lastl];   // block-uniform
            int f = t & 15, rr = t >> 4;
#pragma unroll
            for (int h = 0; h < 2; h++) {
                if (valid) {
#pragma unroll
                    for (int jj = 0; jj < 16; jj++) {
                        int j = h * 16 + jj;
                        float vv = sdeg * b2[j];
#pragma unroll
                        for (int k = 0; k < 16; k++) vv = fmaf(a[k], W2[k * 32 + j], vv);
                        srow[t * 17 + jj] = reluf(vv);
                    }
                } else {
#pragma unroll
                    for (int jj = 0; jj < 16; jj++) srow[t * 17 + jj] = 0.f;
                }
                __syncthreads();
                for (int g = g0; g <= g1; g++) {
                    float p = 0.f;
#pragma unroll
                    for (int q = 0; q < 16; q++) {
                        int n = rr + 16 * q;
                        p += (sbat[n] == g) ? srow[n * 17 + f] : 0.f;
                    }
                    spart[rr * 16 + f] = p;
                    __syncthreads();
                    if (rr == 0) {
                        float tot = 0.f;
#pragma unroll
                        for (int q = 0; q < 16; q++) tot += spart[q * 16 + f];
                        unsafeAtomicAdd(&pooled[32 * (size_t)g + h * 16 + f], tot);
                    }
                    __syncthreads();
                }
                __syncthreads();   // srow reuse fence
            }
        }
    }
    gridSync(bar, bar + 1, nb, 2);

    // ---- P4: mean + MLP head, one thread per graph ----
    int g = bid * TPB + t;
    if (g < G) {
        int lo = lower_bound(batch, N, g);
        int hi = lower_bound(batch, N, g + 1);
        int cnt = hi - lo;
        float inv = 1.f / (float)(cnt > 1 ? cnt : 1);
        float p[32];
#pragma unroll
        for (int i = 0; i < 32; i++) p[i] = pooled[32 * (size_t)g + i] * inv;
        float acc = bf2[0];
#pragma unroll
        for (int j = 0; j < 16; j++) {
            float v = bf1[j];
#pragma unroll
            for (int i = 0; i < 32; i++) v = fmaf(p[i], Wf1[i * 16 + j], v);
            acc = fmaf(reluf(v), Wf2[j], acc);
        }
        out[g] = acc;
    }
}

static inline size_t align256(size_t v) { return (v + 255) & ~(size_t)255; }

extern "C" void kernel_launch(void* const* d_in, const int* in_sizes, int n_in,
                              void* d_out, int out_size, void* d_ws, size_t ws_size,
                              hipStream_t stream) {
    const float* x    = (const float*)d_in[0];
    const int*   ei   = (const int*)d_in[1];
    const int*   batch= (const int*)d_in[2];
    const float* W1   = (const float*)d_in[3];
    const float* b1   = (const float*)d_in[4];
    const float* W2   = (const float*)d_in[5];
    const float* b2   = (const float*)d_in[6];
    const float* Wf1  = (const float*)d_in[7];
    const float* bf1  = (const float*)d_in[8];
    const float* Wf2  = (const float*)d_in[9];
    const float* bf2  = (const float*)d_in[10];
    float* out = (float*)d_out;

    const int N = in_sizes[0] / 2;
    const int E = in_sizes[1] / 2;
    const int G = out_size;
    const int* src = ei;        // edge_index[0]
    const int* dst = ei + E;    // edge_index[1]

    const int NSB = (N + SBK - 1) >> SBK_BITS;       // buckets (977 for N=500k)
    const int NB1 = (E + PE1 - 1) / PE1;             // pass-1 chunks (611)

    // workspace layout (~40 MB); bar + curx contiguous for one memset
    char* w = (char*)d_ws;
    int*   bar    = (int*)w;    w += align256(2 * sizeof(int));
    int*   curx   = (int*)w;    w += align256((size_t)8 * NSBX * sizeof(int));
    int*   supEnd = (int*)w;    w += align256((size_t)NSBX * sizeof(int));
    int*   rowptr = (int*)w;    w += align256((size_t)N * sizeof(int));
    uint2* ninfo  = (uint2*)w;  w += align256((size_t)N * sizeof(uint2));
    float* pooled = (float*)w;  w += align256((size_t)G * 32 * sizeof(float));
    int*   part1x = (int*)w;    w += align256((size_t)8 * NSBX * CAPX * sizeof(int));
    int*   partS  = (int*)w;    w += align256((size_t)NSBX * CAPS * sizeof(int));

    // grid <= guaranteed co-residency (4 blocks/CU x 256 CU = 1024)
    int grid = NSB < 1024 ? NSB : 1024;

    hipMemsetAsync(bar, 0, align256(2 * sizeof(int)) + (size_t)8 * NSBX * sizeof(int), stream);
    kFused<<<grid, TPB, 0, stream>>>(src, dst, x, batch, W1, b1, W2, b2,
                                     Wf1, bf1, Wf2, bf2,
                                     bar, curx, supEnd, rowptr, ninfo, pooled,
                                     part1x, partS, out, N, E, G, NSB, NB1);
}

// Round 20
// 193.906 us; speedup vs baseline: 4.4623x; 4.4623x over previous
//
#include <hip/hip_runtime.h>

// GNN_MLP R20 = R18 verbatim (best: 196.2us). R19 falsified single-kernel
// fusion: software grid barriers across 8 non-coherent XCDs cost ~600us
// (AGENT-scope acquire polling serializes at the device coherence point) —
// kernel boundaries (~5-8us) are the cheap primitive on MI355X.
// Structure: [kPart1] LDS-hist XCD-sliced scatter (block reservation keeps
// 64B write runs; R15 falsified cursor-only) -> [kPart2C1] per-bucket
// counting sort + fused conv1 (register accumulate; R10 falsified LDS float
// atomics: 3.3cyc/lane-op was the 222us plateau) -> [kConv2] register
// message accumulation over CSR + half-tile LDS epilogue (19.5KB, R17
// falsified launch_bounds(,8): VGPR squeeze -> scratch spill) + fused
// mean-pool partials -> [kMLP].
// ninfo packs (a0, a1, indeg<=31 in a1 low-5 mantissa bits) into 8B (4MB,
// L2-resident gather array; R6/R7 showed 64B h1 gathers structurally miss).
// Algebra: conv = segsum((h@W+b)[src],dst) = segsum(h[src])@W + indeg*b.

#define TPB 256
#define SBK_BITS 9            // bucket = 512 nodes
#define SBK 512
#define NSBX 1024             // max buckets (N < 524288)
#define CAPX 576              // per (slice,bucket) capacity: mean 320, +14 sigma
#define CAPS 3072             // sorted edges per bucket: mean 2560, +10 sigma
#define PE1 4096              // edges per pass-1 block

typedef unsigned int uint32;

__device__ __forceinline__ float reluf(float v) { return v > 0.f ? v : 0.f; }

// pass 1: LDS-hist sliced scatter. word = src<<9 | dst&511.
__global__ void kPart1(const int* __restrict__ src, const int* __restrict__ dst,
                       int* __restrict__ curx, int* __restrict__ part1x, int E) {
    __shared__ int h[NSBX];
    for (int i = threadIdx.x; i < NSBX; i += TPB) h[i] = 0;
    __syncthreads();
    int base = blockIdx.x * PE1;
    int end = base + PE1 < E ? base + PE1 : E;
    for (int e = base + threadIdx.x; e < end; e += TPB)
        atomicAdd(&h[dst[e] >> SBK_BITS], 1);
    __syncthreads();
    int slice = blockIdx.x & 7;                 // ~XCD under round-robin dispatch
    int* cur = curx + slice * NSBX;
    int rbase = slice * (NSBX * CAPX);
    for (int i = threadIdx.x; i < NSBX; i += TPB) {
        int c = h[i];
        if (c) h[i] = i * CAPX + atomicAdd(&cur[i], c);
    }
    __syncthreads();
    for (int e = base + threadIdx.x; e < end; e += TPB) {
        int d = dst[e];
        int b = d >> SBK_BITS;
        int pos = atomicAdd(&h[b], 1);
        if (pos < (b + 1) * CAPX)               // overflow guard
            part1x[rbase + pos] = (src[e] << SBK_BITS) | (d & (SBK - 1));
    }
}

// pass 2 + fused conv1 (+ pooled zeroing): LDS hist from 8 slices, scan,
// sort scatter staging sorted src ids in LDS, per-node x accumulation.
__global__ void kPart2C1(const int* __restrict__ curx, const int* __restrict__ part1x,
                         const float* __restrict__ x,
                         int* __restrict__ rowptr, int* __restrict__ supEnd,
                         int* __restrict__ partS, uint2* __restrict__ ninfo,
                         float* __restrict__ pooled, int N, int G) {
    // zero pooled (consumed by kConv2 next kernel; boundary guarantees order)
    int z = blockIdx.x * TPB + threadIdx.x;
    if (z < 32 * G) pooled[z] = 0.f;

    __shared__ int hist[SBK];          // counts -> cursors
    __shared__ int ps[TPB];
    __shared__ int sls[CAPS];          // sorted src ids (12 KB)
    __shared__ int segc[8];
    int sb = blockIdx.x;
    int node0 = sb << SBK_BITS;
    int sbase = sb * CAPS;
    int t = threadIdx.x;
    for (int i = t; i < SBK; i += TPB) hist[i] = 0;
    if (t < 8) {
        int c = curx[t * NSBX + sb];
        segc[t] = c > CAPX ? CAPX : c;
    }
    __syncthreads();
    for (int seg = 0; seg < 8; seg++) {
        const int* p = part1x + seg * (NSBX * CAPX) + sb * CAPX;
        int c = segc[seg];
        for (int i = t; i < c; i += TPB)
            atomicAdd(&hist[p[i] & (SBK - 1)], 1);
    }
    __syncthreads();
    // scan 512 = 256 threads x 2 items
    int v0 = hist[2 * t], v1 = hist[2 * t + 1];
    int s = v0 + v1;
    ps[t] = s;
    __syncthreads();
    for (int off = 1; off < TPB; off <<= 1) {
        int u = (t >= off) ? ps[t - off] : 0;
        __syncthreads();
        ps[t] += u;
        __syncthreads();
    }
    int start0 = ps[t] - s;            // exclusive scan within bucket
    int start1 = start0 + v0;
    int n0 = node0 + 2 * t, n1 = n0 + 1;
    if (n0 < N) rowptr[n0] = sbase + start0;
    if (n1 < N) rowptr[n1] = sbase + start1;
    hist[2 * t] = start0;              // own slots only -> no race
    hist[2 * t + 1] = start1;
    if (t == TPB - 1) supEnd[sb] = sbase + ps[t];
    __syncthreads();
    // sort scatter from 8 slices (1 LDS rtn atomic/edge), staging sls
    for (int seg = 0; seg < 8; seg++) {
        const int* p = part1x + seg * (NSBX * CAPX) + sb * CAPX;
        int c = segc[seg];
        for (int i = t; i < c; i += TPB) {
            int w = p[i];
            int slot = atomicAdd(&hist[w & (SBK - 1)], 1);
            if (slot < CAPS) {
                int sid = w >> SBK_BITS;
                partS[sbase + slot] = sid;
                sls[slot] = sid;
            }
        }
    }
    __syncthreads();
    // fused conv1: 2 nodes per thread, register accumulation over LDS run
#pragma unroll
    for (int half = 0; half < 2; half++) {
        int n = half ? n1 : n0;
        if (n >= N) continue;
        int st = half ? start1 : start0;
        int dg = half ? v1 : v0;
        int en = st + dg; if (en > CAPS) en = CAPS;
        float2 sv = ((const float2*)x)[n];
        float a0 = sv.x, a1 = sv.y;
        for (int e = st; e < en; e++) {
            float2 xv = ((const float2*)x)[sls[e]];
            a0 += xv.x; a1 += xv.y;
        }
        int indeg = dg + 1;                // + self loop
        if (indeg > 31) indeg = 31;        // 5-bit field, P(overflow) ~ 1e-10
        ninfo[n] = make_uint2(__float_as_uint(a0),
                              (__float_as_uint(a1) & ~31u) | (uint32)indeg);
    }
}

__device__ __forceinline__ int rowEnd(const int* __restrict__ rowptr,
                                      const int* __restrict__ supEnd, int i, int N) {
    int nxt = i + 1;
    return (nxt >= N || (nxt & (SBK - 1)) == 0) ? supEnd[i >> SBK_BITS] : rowptr[nxt];
}

__device__ __forceinline__ void addMsg(float* a, uint2 q,
                                       const float* __restrict__ W1,
                                       const float* __restrict__ b1) {
    float n0 = __uint_as_float(q.x);
    float ndeg = (float)(q.y & 31u);
    float n1 = __uint_as_float(q.y & ~31u);
#pragma unroll
    for (int j = 0; j < 16; j++)
        a[j] += reluf(fmaf(n0, W1[j], fmaf(n1, W1[16 + j], ndeg * b1[j])));
}

// conv2 + fused mean-pool; half-tile epilogue reuses one 17.4KB srow buffer.
// launch_bounds(256,4): allocator budget ~128 VGPR (uses ~56, no spill);
// HW occupancy reaches 8 blocks/CU via LDS=19.5KB + VGPR<=64 on its own.
__global__ void __launch_bounds__(TPB, 4)
kConv2(const uint2* __restrict__ ninfo, const int* __restrict__ partS,
       const int* __restrict__ rowptr, const int* __restrict__ supEnd,
       const int* __restrict__ batch,
       const float* __restrict__ W1, const float* __restrict__ b1,
       const float* __restrict__ W2, const float* __restrict__ b2,
       float* __restrict__ pooled, int N) {
    __shared__ float srow[TPB * 17];     // 17.4 KB, one 16-feature half-tile
    __shared__ int sbat[TPB];
    __shared__ float spart[16 * 16];
    int node0 = blockIdx.x * TPB;
    int l = threadIdx.x;
    int i = node0 + l;
    bool valid = i < N;
    float a[16];
    float sdeg = 0.f;
    if (valid) {
        int rs = rowptr[i];
        int re = rowEnd(rowptr, supEnd, i, N);
        uint2 p = ninfo[i];
        float s0 = __uint_as_float(p.x);
        sdeg = (float)(p.y & 31u);
        float s1 = __uint_as_float(p.y & ~31u);
#pragma unroll
        for (int j = 0; j < 16; j++)
            a[j] = reluf(fmaf(s0, W1[j], fmaf(s1, W1[16 + j], sdeg * b1[j])));
        int e = rs;
        for (; e + 4 <= re; e += 4) {    // 4 gathers in flight
            int w0 = partS[e], w1 = partS[e + 1], w2 = partS[e + 2], w3 = partS[e + 3];
            uint2 q0 = ninfo[w0], q1 = ninfo[w1], q2 = ninfo[w2], q3 = ninfo[w3];
            addMsg(a, q0, W1, b1);
            addMsg(a, q1, W1, b1);
            addMsg(a, q2, W1, b1);
            addMsg(a, q3, W1, b1);
        }
        for (; e < re; e++)
            addMsg(a, ninfo[partS[e]], W1, b1);
        sbat[l] = batch[i];
    } else {
#pragma unroll
        for (int j = 0; j < 16; j++) a[j] = 0.f;
        sbat[l] = -1;
    }
    __syncthreads();
    int lastl = N - 1 - node0;
    if (lastl > TPB - 1) lastl = TPB - 1;
    int g0 = sbat[0], g1 = sbat[lastl];     // block-uniform
    int f = l & 15, rr = l >> 4;
#pragma unroll
    for (int h = 0; h < 2; h++) {
        if (valid) {
#pragma unroll
            for (int jj = 0; jj < 16; jj++) {
                int j = h * 16 + jj;
                float vv = sdeg * b2[j];
#pragma unroll
                for (int k = 0; k < 16; k++) vv = fmaf(a[k], W2[k * 32 + j], vv);
                srow[l * 17 + jj] = reluf(vv);
            }
        } else {
#pragma unroll
            for (int jj = 0; jj < 16; jj++) srow[l * 17 + jj] = 0.f;
        }
        __syncthreads();
        for (int g = g0; g <= g1; g++) {
            float p = 0.f;
#pragma unroll
            for (int q = 0; q < 16; q++) {
                int n = rr + 16 * q;
                p += (sbat[n] == g) ? srow[n * 17 + f] : 0.f;
            }
            spart[rr * 16 + f] = p;
            __syncthreads();
            if (rr == 0) {
                float tot = 0.f;
#pragma unroll
                for (int q = 0; q < 16; q++) tot += spart[q * 16 + f];
                unsafeAtomicAdd(&pooled[32 * (size_t)g + h * 16 + f], tot);
            }
            __syncthreads();
        }
        __syncthreads();   // srow reuse fence before next half
    }
}

__device__ __forceinline__ int lower_bound(const int* __restrict__ a, int n, int v) {
    int lo = 0, hi = n;
    while (lo < hi) {
        int m = (lo + hi) >> 1;
        if (a[m] < v) lo = m + 1; else hi = m;
    }
    return lo;
}

// final: mean (count via binary search on sorted batch) + MLP head
__global__ void kMLP(const float* __restrict__ pooled, const int* __restrict__ batch,
                     const float* __restrict__ Wf1, const float* __restrict__ bf1,
                     const float* __restrict__ Wf2, const float* __restrict__ bf2,
                     float* __restrict__ out, int N, int G) {
    int g = blockIdx.x * blockDim.x + threadIdx.x;
    if (g >= G) return;
    int lo = lower_bound(batch, N, g);
    int hi = lower_bound(batch, N, g + 1);
    int cnt = hi - lo;
    float inv = 1.f / (float)(cnt > 1 ? cnt : 1);
    float p[32];
#pragma unroll
    for (int i = 0; i < 32; i++) p[i] = pooled[32 * (size_t)g + i] * inv;
    float acc = bf2[0];
#pragma unroll
    for (int j = 0; j < 16; j++) {
        float v = bf1[j];
#pragma unroll
        for (int i = 0; i < 32; i++) v = fmaf(p[i], Wf1[i * 16 + j], v);
        acc = fmaf(reluf(v), Wf2[j], acc);
    }
    out[g] = acc;
}

static inline size_t align256(size_t v) { return (v + 255) & ~(size_t)255; }

extern "C" void kernel_launch(void* const* d_in, const int* in_sizes, int n_in,
                              void* d_out, int out_size, void* d_ws, size_t ws_size,
                              hipStream_t stream) {
    const float* x    = (const float*)d_in[0];
    const int*   ei   = (const int*)d_in[1];
    const int*   batch= (const int*)d_in[2];
    const float* W1   = (const float*)d_in[3];
    const float* b1   = (const float*)d_in[4];
    const float* W2   = (const float*)d_in[5];
    const float* b2   = (const float*)d_in[6];
    const float* Wf1  = (const float*)d_in[7];
    const float* bf1  = (const float*)d_in[8];
    const float* Wf2  = (const float*)d_in[9];
    const float* bf2  = (const float*)d_in[10];
    float* out = (float*)d_out;

    const int N = in_sizes[0] / 2;
    const int E = in_sizes[1] / 2;
    const int G = out_size;
    const int* src = ei;        // edge_index[0]
    const int* dst = ei + E;    // edge_index[1]

    const int NSB = (N + SBK - 1) >> SBK_BITS;       // buckets (<=1024)
    const int NFB = (N + TPB - 1) / TPB;             // conv2 blocks

    // workspace layout (~40 MB)
    char* w = (char*)d_ws;
    int*   curx   = (int*)w;    w += align256((size_t)8 * NSBX * sizeof(int));
    int*   supEnd = (int*)w;    w += align256((size_t)NSBX * sizeof(int));
    int*   rowptr = (int*)w;    w += align256((size_t)N * sizeof(int));
    uint2* ninfo  = (uint2*)w;  w += align256((size_t)N * sizeof(uint2));
    float* pooled = (float*)w;  w += align256((size_t)G * 32 * sizeof(float));
    int*   part1x = (int*)w;    w += align256((size_t)8 * NSBX * CAPX * sizeof(int));
    int*   partS  = (int*)w;    w += align256((size_t)NSBX * CAPS * sizeof(int));

    const int nb1 = (E + PE1 - 1) / PE1;

    hipMemsetAsync(curx, 0, (size_t)8 * NSBX * sizeof(int), stream);
    kPart1  <<<nb1, TPB, 0, stream>>>(src, dst, curx, part1x, E);
    kPart2C1<<<NSB, TPB, 0, stream>>>(curx, part1x, x, rowptr, supEnd, partS,
                                      ninfo, pooled, N, G);
    kConv2  <<<NFB, TPB, 0, stream>>>(ninfo, partS, rowptr, supEnd, batch,
                                      W1, b1, W2, b2, pooled, N);
    kMLP    <<<(G + TPB - 1) / TPB, TPB, 0, stream>>>(pooled, batch, Wf1, bf1, Wf2, bf2, out, N, G);
}